// Round 1
// baseline (262.395 us; speedup 1.0000x reference)
//
#include <hip/hip_runtime.h>
#include <hip/hip_bf16.h>
#include <stdint.h>

#define LN_EPS 1e-5f

typedef __attribute__((ext_vector_type(8))) short bf16x8;
typedef __attribute__((ext_vector_type(4))) float f32x4;
typedef __attribute__((ext_vector_type(4))) short short4v;

__device__ __forceinline__ short f2bf(float x) {
    union { __hip_bfloat16 b; short s; } u;
    u.b = __float2bfloat16(x);   // RNE convert
    return u.s;
}

__device__ __forceinline__ float sigm(float x) { return 1.f / (1.f + __expf(-x)); }
__device__ __forceinline__ float tanh_f(float x) {
    x = fminf(15.f, fmaxf(-15.f, x));
    float e = __expf(2.f * x);
    return (e - 1.f) / (e + 1.f);
}

// ---------------------------------------------------------------------------
// Pack two f32 [rows][1024] matrices into one bf16 [rows][2048] concat matrix.
// Hardcoded c0 = c1 = 1024 (C = 2048) so index math is shifts/masks.
// ---------------------------------------------------------------------------
__global__ __launch_bounds__(256)
void pack_cat_bf16(const float* __restrict__ s0, const float* __restrict__ s1,
                   short* __restrict__ dst, int rows)
{
    const long total4 = (long)rows * 2048 / 4;
    for (long q = blockIdx.x * (long)blockDim.x + threadIdx.x; q < total4;
         q += (long)gridDim.x * blockDim.x) {
        long n = q << 2;               // element index in dst
        long r = n >> 11;              // row (C = 2048)
        int  k = (int)(n & 2047);      // col
        const float* src = (k < 1024) ? (s0 + (r << 10) + k)
                                      : (s1 + (r << 10) + (k - 1024));
        float4 v = *(const float4*)src;
        short4v o;
        o.x = f2bf(v.x); o.y = f2bf(v.y); o.z = f2bf(v.z); o.w = f2bf(v.w);
        *(short4v*)(dst + n) = o;
    }
}

// ---------------------------------------------------------------------------
// C[M,N] f32 = A[M,K] bf16 @ B[N,K]^T bf16   (m97 structure: 128x128 tile,
// BK=32, 4 waves in 2x2, global_load_lds width-16 staging, 16x16x32 MFMA)
// ---------------------------------------------------------------------------
#define BM 128
#define BN 128
#define BKK 32

__global__ __launch_bounds__(256)
void gemm_bt_bf16(const short* __restrict__ A, const short* __restrict__ B,
                  float* __restrict__ C, int M, int N, int K)
{
    __shared__ short sA[BM * BKK];   // 8 KB, row-major [128][32]
    __shared__ short sB[BN * BKK];   // 8 KB
    const int t    = threadIdx.x;
    const int lane = t & 63;
    const int wave = t >> 6;
    const int wr   = wave >> 1;      // wave row in 2x2
    const int wc   = wave & 1;       // wave col
    const int brow = blockIdx.y * BM;
    const int bcol = blockIdx.x * BN;

    const int r4 = t >> 2;           // 0..63: row within a 64-row half-tile
    const int k8 = (t & 3) << 3;     // 0/8/16/24: bf16 k-offset (16B per lane)

    const short* Ag = A + (long)(brow + r4) * K + k8;
    const short* Bg = B + (long)(bcol + r4) * K + k8;

    auto sA3 = (__attribute__((address_space(3))) char*)sA;
    auto sB3 = (__attribute__((address_space(3))) char*)sB;
    const int ldsOff = wave * 1024;  // byte base per wave (wave-uniform)

    f32x4 acc[4][4] = {};

    // LDS read base: row = wr*64 + (lane&15), kbyte = (lane>>4)*16
    const short* sAr = sA + (wr * 64 + (lane & 15)) * BKK + ((lane >> 4) << 3);
    const short* sBr = sB + (wc * 64 + (lane & 15)) * BKK + ((lane >> 4) << 3);

    for (int kt = 0; kt < K; kt += BKK) {
        __syncthreads();   // prior ds_reads done before overwrite
        // A tile: 2 issues x (256 lanes * 16B) = 8 KB
        __builtin_amdgcn_global_load_lds(
            (const __attribute__((address_space(1))) void*)(Ag + kt),
            (__attribute__((address_space(3))) void*)(sA3 + ldsOff), 16, 0, 0);
        __builtin_amdgcn_global_load_lds(
            (const __attribute__((address_space(1))) void*)(Ag + kt + 64 * K),
            (__attribute__((address_space(3))) void*)(sA3 + 4096 + ldsOff), 16, 0, 0);
        __builtin_amdgcn_global_load_lds(
            (const __attribute__((address_space(1))) void*)(Bg + kt),
            (__attribute__((address_space(3))) void*)(sB3 + ldsOff), 16, 0, 0);
        __builtin_amdgcn_global_load_lds(
            (const __attribute__((address_space(1))) void*)(Bg + kt + 64 * K),
            (__attribute__((address_space(3))) void*)(sB3 + 4096 + ldsOff), 16, 0, 0);
        __syncthreads();   // drains vmcnt(0) so LDS is valid

        bf16x8 af[4], bfr[4];
        #pragma unroll
        for (int m = 0; m < 4; ++m) af[m]  = *(const bf16x8*)(sAr + m * 16 * BKK);
        #pragma unroll
        for (int n = 0; n < 4; ++n) bfr[n] = *(const bf16x8*)(sBr + n * 16 * BKK);

        #pragma unroll
        for (int m = 0; m < 4; ++m)
            #pragma unroll
            for (int n = 0; n < 4; ++n)
                acc[m][n] = __builtin_amdgcn_mfma_f32_16x16x32_bf16(
                    af[m], bfr[n], acc[m][n], 0, 0, 0);
    }

    // C/D layout (m89-verified): col = lane&15, row = (lane>>4)*4 + j
    const int row0 = brow + wr * 64 + ((lane >> 4) << 2);
    const int col0 = bcol + wc * 64 + (lane & 15);
    #pragma unroll
    for (int m = 0; m < 4; ++m)
        #pragma unroll
        for (int n = 0; n < 4; ++n) {
            float* Cp = C + (long)(row0 + m * 16) * N + col0 + n * 16;
            #pragma unroll
            for (int j = 0; j < 4; ++j)
                Cp[(long)j * N] = acc[m][n][j];
        }
}

// ---------------------------------------------------------------------------
// Per-row LayerNorm over 4096 gates + LSTM activations. One block per row.
// ---------------------------------------------------------------------------
__global__ __launch_bounds__(256)
void ln_act_kernel(const float* __restrict__ gates,
                   const float* __restrict__ b_ih, const float* __restrict__ b_hh,
                   const float* __restrict__ gamma, const float* __restrict__ beta,
                   const float* __restrict__ c,
                   float* __restrict__ out_h, float* __restrict__ out_c)
{
    __shared__ float sg[4096];       // 16 KB: biased gate row
    __shared__ float rs[4], rq[4];
    const int b = blockIdx.x;
    const int t = threadIdx.x;
    const float4* grow = (const float4*)(gates + ((long)b << 12));
    const float4* bi4  = (const float4*)b_ih;
    const float4* bh4  = (const float4*)b_hh;

    float sum = 0.f, sq = 0.f;
    #pragma unroll
    for (int j = 0; j < 4; ++j) {
        int idx = t + j * 256;       // float4 index 0..1023
        float4 v  = grow[idx];
        float4 bi = bi4[idx];
        float4 bh = bh4[idx];
        v.x += bi.x + bh.x;  v.y += bi.y + bh.y;
        v.z += bi.z + bh.z;  v.w += bi.w + bh.w;
        ((float4*)sg)[idx] = v;
        sum += v.x + v.y + v.z + v.w;
        sq  += v.x * v.x + v.y * v.y + v.z * v.z + v.w * v.w;
    }
    // wave reduce (64 lanes)
    #pragma unroll
    for (int off = 32; off > 0; off >>= 1) {
        sum += __shfl_down(sum, off);
        sq  += __shfl_down(sq, off);
    }
    if ((t & 63) == 0) { rs[t >> 6] = sum; rq[t >> 6] = sq; }
    __syncthreads();                 // also publishes sg
    sum = rs[0] + rs[1] + rs[2] + rs[3];
    sq  = rq[0] + rq[1] + rq[2] + rq[3];
    const float mu   = sum * (1.f / 4096.f);
    const float rstd = rsqrtf(sq * (1.f / 4096.f) - mu * mu + LN_EPS);

    #pragma unroll
    for (int j = 0; j < 4; ++j) {
        int hc = t + j * 256;        // 0..1023
        float iv = (sg[hc]        - mu) * rstd * gamma[hc]        + beta[hc];
        float fv = (sg[1024 + hc] - mu) * rstd * gamma[1024 + hc] + beta[1024 + hc];
        float gv = (sg[2048 + hc] - mu) * rstd * gamma[2048 + hc] + beta[2048 + hc];
        float ov = (sg[3072 + hc] - mu) * rstd * gamma[3072 + hc] + beta[3072 + hc];
        float cc = c[((long)b << 10) + hc];
        float nc = sigm(fv) * cc + sigm(iv) * tanh_f(gv);
        float nh = sigm(ov) * tanh_f(nc);
        out_h[((long)b << 10) + hc] = nh;
        out_c[((long)b << 10) + hc] = nc;
    }
}

// ---------------------------------------------------------------------------
extern "C" void kernel_launch(void* const* d_in, const int* in_sizes, int n_in,
                              void* d_out, int out_size, void* d_ws, size_t ws_size,
                              hipStream_t stream)
{
    const float* x    = (const float*)d_in[0];
    const float* h    = (const float*)d_in[1];
    const float* c    = (const float*)d_in[2];
    const float* w_ih = (const float*)d_in[3];
    const float* w_hh = (const float*)d_in[4];
    const float* b_ih = (const float*)d_in[5];
    const float* b_hh = (const float*)d_in[6];
    const float* gam  = (const float*)d_in[7];
    const float* bet  = (const float*)d_in[8];
    float* out = (float*)d_out;
    (void)in_sizes; (void)n_in; (void)out_size; (void)ws_size;

    const int B = 4096, H = 1024;
    const int K = 2048;      // I + H
    const int G = 4096;      // 4*H

    char*  ws    = (char*)d_ws;
    short* Acat  = (short*)ws;                                 // 16 MiB bf16 [B][2048]
    short* Wcat  = (short*)(ws + (size_t)16 * 1024 * 1024);    // 16 MiB bf16 [G][2048]
    float* gates = (float*)(ws + (size_t)32 * 1024 * 1024);    // 64 MiB f32  [B][G]

    pack_cat_bf16<<<1024, 256, 0, stream>>>(x, h, Acat, B);
    pack_cat_bf16<<<1024, 256, 0, stream>>>(w_ih, w_hh, Wcat, G);

    dim3 grid(G / BN, B / BM);
    gemm_bt_bf16<<<grid, 256, 0, stream>>>(Acat, Wcat, gates, B, G, K);

    ln_act_kernel<<<B, 256, 0, stream>>>(gates, b_ih, b_hh, gam, bet, c,
                                         out, out + (size_t)B * H);
}

// Round 4
// 233.361 us; speedup vs baseline: 1.1244x; 1.1244x over previous
//
#include <hip/hip_runtime.h>
#include <hip/hip_bf16.h>
#include <stdint.h>

#define LN_EPS 1e-5f

typedef __attribute__((ext_vector_type(8))) short bf16x8;
typedef __attribute__((ext_vector_type(4))) float f32x4;
typedef __attribute__((ext_vector_type(4))) short short4v;

__device__ __forceinline__ short f2bf(float x) {
    union { __hip_bfloat16 b; short s; } u;
    u.b = __float2bfloat16(x);
    return u.s;
}
__device__ __forceinline__ float sigm(float x) { return 1.f / (1.f + __expf(-x)); }
__device__ __forceinline__ float tanh_f(float x) {
    x = fminf(15.f, fmaxf(-15.f, x));
    float e = __expf(2.f * x);
    return (e - 1.f) / (e + 1.f);
}

// ---------------------------------------------------------------------------
// Pack two f32 [rows][1024] matrices into one bf16 [rows][2048] concat matrix.
// ---------------------------------------------------------------------------
__global__ __launch_bounds__(256)
void pack_cat_bf16(const float* __restrict__ s0, const float* __restrict__ s1,
                   short* __restrict__ dst, int rows)
{
    const long total4 = (long)rows * 2048 / 4;
    for (long q = blockIdx.x * (long)blockDim.x + threadIdx.x; q < total4;
         q += (long)gridDim.x * blockDim.x) {
        long n = q << 2;
        long r = n >> 11;
        int  k = (int)(n & 2047);
        const float* src = (k < 1024) ? (s0 + (r << 10) + k)
                                      : (s1 + (r << 10) + (k - 1024));
        float4 v = *(const float4*)src;
        short4v o;
        o.x = f2bf(v.x); o.y = f2bf(v.y); o.z = f2bf(v.z); o.w = f2bf(v.w);
        *(short4v*)(dst + n) = o;
    }
}

// ---------------------------------------------------------------------------
// 256x256 8-phase GEMM (T2 st_16x32 swizzle + T3/T4 counted vmcnt + T5 setprio)
// C[4096,4096] f32 = A[4096,2048] bf16 @ B[4096,2048]^T bf16
// 512 threads = 8 waves (2M x 4N), BK=64, 128 KB LDS double-buffer.
//
// Staging schedule (race-audited): per-region LAST READ phases are
//   a0: P3 (wr=0 aF-hi), a1: P3 (wr=1), b0: P2 (wc01 bF[1]), b1: P2 (wc23).
// Same-buffer (tile t+2) stages therefore go at:
//   P3: b0(t+2); P4: b1(t+2)+a0(t+2); next-tile P1: a1 (as a1(t+1), other buf).
// vmcnt(6) at P4 completes the 8 oldest loads = all 4 halves of tile t+1.
// ---------------------------------------------------------------------------
#define SWZ(x) ((x) ^ ((((x) >> 9) & 1) << 5))

__device__ __forceinline__ void stage_half(const short* __restrict__ G, int rowBase,
                                           int t, char* halfRegion, int tid)
{
    // linear LDS dest (wave-uniform base + lane*16); inverse-swizzled global src
    #pragma unroll
    for (int j = 0; j < 2; ++j) {
        const int p   = j * 8192 + tid * 16;     // physical byte in 16KB half
        const int l   = SWZ(p);                  // logical byte (involution)
        const int row = l >> 7;                  // 128B row stride
        const int kel = (l & 127) >> 1;
        const short* src = G + (size_t)(rowBase + row) * 2048 + t * 64 + kel;
        __builtin_amdgcn_global_load_lds(
            (const __attribute__((address_space(1))) void*)src,
            (__attribute__((address_space(3))) void*)(halfRegion + j * 8192 + ((tid >> 6) << 10)),
            16, 0, 0);
    }
}

__device__ __forceinline__ bf16x8 ldsRead(const char* region, int logical)
{
    return *(const bf16x8*)(region + SWZ(logical));
}

#define BARR()      __builtin_amdgcn_s_barrier()
#define WAIT_LGKM() do { asm volatile("s_waitcnt lgkmcnt(0)" ::: "memory"); \
                         __builtin_amdgcn_sched_barrier(0); } while (0)
#define WAIT_VM6()  asm volatile("s_waitcnt vmcnt(6)" ::: "memory")
#define WAIT_VM0()  asm volatile("s_waitcnt vmcnt(0)" ::: "memory")
#define MFMA16(a, b, c) __builtin_amdgcn_mfma_f32_16x16x32_bf16((a), (b), (c), 0, 0, 0)

__global__ __launch_bounds__(512, 2)
void gemm256_8p(const short* __restrict__ A, const short* __restrict__ B,
                float* __restrict__ C)
{
    __shared__ __align__(1024) char smem[131072];  // [2 buf][A 32KB | B 32KB]
    const int tid  = threadIdx.x;
    const int lane = tid & 63;
    const int wave = tid >> 6;
    const int wr = wave >> 2;          // 0..1  (128-row stripe)
    const int wc = wave & 3;           // 0..3  (64-col stripe)
    const int bx = blockIdx.x & 15, by = blockIdx.x >> 4;
    const int brow = by * 256, bcol = bx * 256;
    const int NT = 32;                 // K=2048 / BK=64

    // per-lane logical byte bases within a [256][64]bf16 region (128B rows)
    const int aBase = (wr * 128 + (lane & 15)) * 128 + ((lane >> 4) << 4);
    const int bBase = (wc * 64  + (lane & 15)) * 128 + ((lane >> 4) << 4);

    f32x4 acc[8][4] = {};
    bf16x8 aF[4][2], bF[2][2][2];

    char* Areg0 = smem;             char* Breg0 = smem + 32768;
    char* Areg1 = smem + 65536;     char* Breg1 = smem + 65536 + 32768;

    // ---- prologue: tile0 fully + {b0,b1,a0}(1); vmcnt(6) leaves those 3 in flight
    stage_half(A, brow +   0, 0, Areg0 +     0, tid);   // a0(0)
    stage_half(A, brow + 128, 0, Areg0 + 16384, tid);   // a1(0)
    stage_half(B, bcol +   0, 0, Breg0 +     0, tid);   // b0(0)
    stage_half(B, bcol + 128, 0, Breg0 + 16384, tid);   // b1(0)
    stage_half(B, bcol +   0, 1, Breg1 +     0, tid);   // b0(1)
    stage_half(B, bcol + 128, 1, Breg1 + 16384, tid);   // b1(1)
    stage_half(A, brow +   0, 1, Areg1 +     0, tid);   // a0(1)
    WAIT_VM6();                                          // tile0 complete
    BARR();

    for (int it = 0; it < 16; ++it) {
        const int t0 = it * 2;
        #pragma unroll
        for (int hb = 0; hb < 2; ++hb) {
            const int t = t0 + hb;
            const char* Ar = hb ? Areg1 : Areg0;   // compute buffer = t&1 = hb
            const char* Br = hb ? Breg1 : Breg0;
            char* ArN = hb ? Areg0 : Areg1;        // buffer of tile t+1
            char* AwC = hb ? Areg1 : Areg0;        // buffer of tile t+2 (= current)
            char* BwC = hb ? Breg1 : Breg0;

            // ---- phase 1: q(mh0,nh0) — 12 ds_reads, stage a1(t+1) [other buf]
            #pragma unroll
            for (int m = 0; m < 4; ++m)
                #pragma unroll
                for (int ks = 0; ks < 2; ++ks)
                    aF[m][ks] = ldsRead(Ar, aBase + m * 2048 + ks * 64);
            #pragma unroll
            for (int n = 0; n < 2; ++n)
                #pragma unroll
                for (int ks = 0; ks < 2; ++ks)
                    bF[0][n][ks] = ldsRead(Br, bBase + n * 2048 + ks * 64);
            if (t + 1 < NT) stage_half(A, brow + 128, t + 1, ArN + 16384, tid);
            BARR(); WAIT_LGKM();
            __builtin_amdgcn_s_setprio(1);
            #pragma unroll
            for (int m = 0; m < 4; ++m)
                #pragma unroll
                for (int n = 0; n < 2; ++n)
                    #pragma unroll
                    for (int ks = 0; ks < 2; ++ks)
                        acc[m][n] = MFMA16(aF[m][ks], bF[0][n][ks], acc[m][n]);
            __builtin_amdgcn_s_setprio(0);
            BARR();

            // ---- phase 2: q(mh0,nh1) — 4 ds_reads, NO stage (a0 race fix)
            #pragma unroll
            for (int n = 0; n < 2; ++n)
                #pragma unroll
                for (int ks = 0; ks < 2; ++ks)
                    bF[1][n][ks] = ldsRead(Br, bBase + (2 + n) * 2048 + ks * 64);
            BARR(); WAIT_LGKM();
            __builtin_amdgcn_s_setprio(1);
            #pragma unroll
            for (int m = 0; m < 4; ++m)
                #pragma unroll
                for (int n = 0; n < 2; ++n)
                    #pragma unroll
                    for (int ks = 0; ks < 2; ++ks)
                        acc[m][2 + n] = MFMA16(aF[m][ks], bF[1][n][ks], acc[m][2 + n]);
            __builtin_amdgcn_s_setprio(0);
            BARR();

            // ---- phase 3: q(mh1,nh1) — 8 ds_reads (aF-hi), stage b0(t+2)
            //      (B-lo reads all completed in phases 1-2)
            #pragma unroll
            for (int m = 0; m < 4; ++m)
                #pragma unroll
                for (int ks = 0; ks < 2; ++ks)
                    aF[m][ks] = ldsRead(Ar, aBase + (4 + m) * 2048 + ks * 64);
            if (t + 2 < NT) stage_half(B, bcol + 0, t + 2, BwC + 0, tid);
            BARR(); WAIT_LGKM();
            __builtin_amdgcn_s_setprio(1);
            #pragma unroll
            for (int m = 0; m < 4; ++m)
                #pragma unroll
                for (int n = 0; n < 2; ++n)
                    #pragma unroll
                    for (int ks = 0; ks < 2; ++ks)
                        acc[4 + m][2 + n] = MFMA16(aF[m][ks], bF[1][n][ks], acc[4 + m][2 + n]);
            __builtin_amdgcn_s_setprio(0);
            BARR();

            // ---- phase 4: q(mh1,nh0) — 0 ds_reads; stage b1(t+2)+a0(t+2)
            //      (A reads all completed in phases 1-3); counted vmcnt
            if (t + 2 < NT) {
                stage_half(B, bcol + 128, t + 2, BwC + 16384, tid);
                stage_half(A, brow +   0, t + 2, AwC +     0, tid);
                WAIT_VM6();     // completes all 4 halves of tile t+1
            } else {
                WAIT_VM0();     // tail drain (tiles 30,31)
            }
            BARR(); WAIT_LGKM();
            __builtin_amdgcn_s_setprio(1);
            #pragma unroll
            for (int m = 0; m < 4; ++m)
                #pragma unroll
                for (int n = 0; n < 2; ++n)
                    #pragma unroll
                    for (int ks = 0; ks < 2; ++ks)
                        acc[4 + m][n] = MFMA16(aF[m][ks], bF[0][n][ks], acc[4 + m][n]);
            __builtin_amdgcn_s_setprio(0);
            BARR();
        }
    }

    // ---- epilogue: C/D layout col=lane&15, row=(lane>>4)*4+j (m89-verified)
    const int row0 = brow + wr * 128 + ((lane >> 4) << 2);
    const int col0 = bcol + wc * 64 + (lane & 15);
    #pragma unroll
    for (int m = 0; m < 8; ++m)
        #pragma unroll
        for (int n = 0; n < 4; ++n) {
            float* Cp = C + (size_t)(row0 + m * 16) * 4096 + col0 + n * 16;
            #pragma unroll
            for (int j = 0; j < 4; ++j)
                Cp[(size_t)j * 4096] = acc[m][n][j];
        }
}

// ---------------------------------------------------------------------------
// Per-row LayerNorm over 4096 gates + LSTM activations. One block per row.
// ---------------------------------------------------------------------------
__global__ __launch_bounds__(256)
void ln_act_kernel(const float* __restrict__ gates,
                   const float* __restrict__ b_ih, const float* __restrict__ b_hh,
                   const float* __restrict__ gamma, const float* __restrict__ beta,
                   const float* __restrict__ c,
                   float* __restrict__ out_h, float* __restrict__ out_c)
{
    __shared__ float sg[4096];
    __shared__ float rs[4], rq[4];
    const int b = blockIdx.x;
    const int t = threadIdx.x;
    const float4* grow = (const float4*)(gates + ((long)b << 12));
    const float4* bi4  = (const float4*)b_ih;
    const float4* bh4  = (const float4*)b_hh;

    float sum = 0.f, sq = 0.f;
    #pragma unroll
    for (int j = 0; j < 4; ++j) {
        int idx = t + j * 256;
        float4 v  = grow[idx];
        float4 bi = bi4[idx];
        float4 bh = bh4[idx];
        v.x += bi.x + bh.x;  v.y += bi.y + bh.y;
        v.z += bi.z + bh.z;  v.w += bi.w + bh.w;
        ((float4*)sg)[idx] = v;
        sum += v.x + v.y + v.z + v.w;
        sq  += v.x * v.x + v.y * v.y + v.z * v.z + v.w * v.w;
    }
    #pragma unroll
    for (int off = 32; off > 0; off >>= 1) {
        sum += __shfl_down(sum, off);
        sq  += __shfl_down(sq, off);
    }
    if ((t & 63) == 0) { rs[t >> 6] = sum; rq[t >> 6] = sq; }
    __syncthreads();
    sum = rs[0] + rs[1] + rs[2] + rs[3];
    sq  = rq[0] + rq[1] + rq[2] + rq[3];
    const float mu   = sum * (1.f / 4096.f);
    const float rstd = rsqrtf(sq * (1.f / 4096.f) - mu * mu + LN_EPS);

    const float4* sg4 = (const float4*)sg;
    const float4* gm4 = (const float4*)gamma;
    const float4* bt4 = (const float4*)beta;
    float4 vi = sg4[t],        vf = sg4[256 + t];
    float4 vg = sg4[512 + t],  vo = sg4[768 + t];
    float4 gi = gm4[t], gf = gm4[256 + t], gg = gm4[512 + t], go = gm4[768 + t];
    float4 zi = bt4[t], zf = bt4[256 + t], zg = bt4[512 + t], zo = bt4[768 + t];
    float4 cc = ((const float4*)c)[((long)b << 8) + t];
    float4 nh, nc;
    {
        float i0, f0, g0, o0;
        #define DO_COMP(X)                                                    \
            i0 = (vi.X - mu) * rstd * gi.X + zi.X;                            \
            f0 = (vf.X - mu) * rstd * gf.X + zf.X;                            \
            g0 = (vg.X - mu) * rstd * gg.X + zg.X;                            \
            o0 = (vo.X - mu) * rstd * go.X + zo.X;                            \
            nc.X = sigm(f0) * cc.X + sigm(i0) * tanh_f(g0);                   \
            nh.X = sigm(o0) * tanh_f(nc.X);
        DO_COMP(x) DO_COMP(y) DO_COMP(z) DO_COMP(w)
        #undef DO_COMP
    }
    ((float4*)out_h)[((long)b << 8) + t] = nh;
    ((float4*)out_c)[((long)b << 8) + t] = nc;
}

// ---------------------------------------------------------------------------
extern "C" void kernel_launch(void* const* d_in, const int* in_sizes, int n_in,
                              void* d_out, int out_size, void* d_ws, size_t ws_size,
                              hipStream_t stream)
{
    const float* x    = (const float*)d_in[0];
    const float* h    = (const float*)d_in[1];
    const float* c    = (const float*)d_in[2];
    const float* w_ih = (const float*)d_in[3];
    const float* w_hh = (const float*)d_in[4];
    const float* b_ih = (const float*)d_in[5];
    const float* b_hh = (const float*)d_in[6];
    const float* gam  = (const float*)d_in[7];
    const float* bet  = (const float*)d_in[8];
    float* out = (float*)d_out;
    (void)in_sizes; (void)n_in; (void)out_size; (void)ws_size;

    const int B = 4096, H = 1024, G = 4096;

    char*  ws    = (char*)d_ws;
    short* Acat  = (short*)ws;                                 // 16 MiB bf16 [B][2048]
    short* Wcat  = (short*)(ws + (size_t)16 * 1024 * 1024);    // 16 MiB bf16 [G][2048]
    float* gates = (float*)(ws + (size_t)32 * 1024 * 1024);    // 64 MiB f32  [B][G]

    pack_cat_bf16<<<1024, 256, 0, stream>>>(x, h, Acat, B);
    pack_cat_bf16<<<1024, 256, 0, stream>>>(w_ih, w_hh, Wcat, G);

    gemm256_8p<<<dim3(256), dim3(512), 0, stream>>>(Acat, Wcat, gates);

    ln_act_kernel<<<B, 256, 0, stream>>>(gates, b_ih, b_hh, gam, bet, c,
                                         out, out + (size_t)B * H);
}

// Round 6
// 214.779 us; speedup vs baseline: 1.2217x; 1.0865x over previous
//
#include <hip/hip_runtime.h>
#include <hip/hip_bf16.h>
#include <stdint.h>

#define LN_EPS 1e-5f

typedef __attribute__((ext_vector_type(8))) short bf16x8;
typedef __attribute__((ext_vector_type(4))) float f32x4;
typedef __attribute__((ext_vector_type(4))) short short4v;

__device__ __forceinline__ short f2bf(float x) {
    union { __hip_bfloat16 b; short s; } u;
    u.b = __float2bfloat16(x);   // RNE
    return u.s;
}
__device__ __forceinline__ float lo_bf(unsigned v) {
    union { unsigned u; float f; } c; c.u = v << 16; return c.f;
}
__device__ __forceinline__ float hi_bf(unsigned v) {
    union { unsigned u; float f; } c; c.u = v & 0xFFFF0000u; return c.f;
}
__device__ __forceinline__ float sigm(float x) { return 1.f / (1.f + __expf(-x)); }
__device__ __forceinline__ float tanh_f(float x) {
    x = fminf(15.f, fmaxf(-15.f, x));
    float e = __expf(2.f * x);
    return (e - 1.f) / (e + 1.f);
}

// ---------------------------------------------------------------------------
// Fused pack: [x|h] -> Acat bf16[4096][2048], [w_ih|w_hh] -> Wcat bf16[4096][2048]
// ---------------------------------------------------------------------------
__global__ __launch_bounds__(256)
void pack_all_bf16(const float* __restrict__ x, const float* __restrict__ h,
                   const float* __restrict__ wih, const float* __restrict__ whh,
                   short* __restrict__ Acat, short* __restrict__ Wcat)
{
    const int total = 4 * 1024 * 1024;           // float4 quads (A: 2M, W: 2M)
    for (int q = blockIdx.x * blockDim.x + threadIdx.x; q < total;
         q += gridDim.x * blockDim.x) {
        const int  qq  = q & (2 * 1024 * 1024 - 1);
        const bool isW = q >= 2 * 1024 * 1024;
        const float* s0 = isW ? wih : x;
        const float* s1 = isW ? whh : h;
        short* dst = isW ? Wcat : Acat;
        const long n = (long)qq << 2;            // element index
        const long r = n >> 11;                  // row (C=2048)
        const int  k = (int)(n & 2047);
        const float* src = (k < 1024) ? (s0 + (r << 10) + k)
                                      : (s1 + (r << 10) + (k - 1024));
        float4 v = *(const float4*)src;
        short4v o;
        o.x = f2bf(v.x); o.y = f2bf(v.y); o.z = f2bf(v.z); o.w = f2bf(v.w);
        *(short4v*)(dst + n) = o;
    }
}

// ---------------------------------------------------------------------------
// 256x256 8-phase GEMM. T2 swizzle = 3-bit row XOR (Guideline-4 recipe):
//   phys = logical ^ ((row&7)<<4), row = logical>>7 (128B rows).
// Involution touching only bits[6:4]; bits[9:7] (row) untouched -> staging
// inverse-swizzle stays valid. 8 consecutive lanes (8 consecutive rows) at one
// 16B col slot now cover all 8 slots of the row -> conflict-free ds_read_b128.
//
// Staging schedule (race-audited, round-3): P1: a1(t+1); P2: none;
// P3: b0(t+2); P4: b1(t+2)+a0(t+2), then vmcnt(6) (= tile t+1 complete).
// ---------------------------------------------------------------------------
#define SWZ(x) ((x) ^ (((((x) >> 7) & 7)) << 4))

__device__ __forceinline__ void stage_half(const short* __restrict__ G, int rowBase,
                                           int t, char* halfRegion, int tid)
{
    // linear LDS dest (wave-uniform base + lane*16); inverse-swizzled global src
    #pragma unroll
    for (int j = 0; j < 2; ++j) {
        const int p   = j * 8192 + tid * 16;     // physical byte in 16KB half
        const int l   = SWZ(p);                  // logical byte (involution)
        const int row = l >> 7;                  // 128B row stride
        const int kel = (l & 127) >> 1;
        const short* src = G + (size_t)(rowBase + row) * 2048 + t * 64 + kel;
        __builtin_amdgcn_global_load_lds(
            (const __attribute__((address_space(1))) void*)src,
            (__attribute__((address_space(3))) void*)(halfRegion + j * 8192 + ((tid >> 6) << 10)),
            16, 0, 0);
    }
}

__device__ __forceinline__ bf16x8 ldsRead(const char* region, int logical)
{
    return *(const bf16x8*)(region + SWZ(logical));
}

#define BARR()      __builtin_amdgcn_s_barrier()
#define WAIT_LGKM() do { asm volatile("s_waitcnt lgkmcnt(0)" ::: "memory"); \
                         __builtin_amdgcn_sched_barrier(0); } while (0)
#define WAIT_VM6()  asm volatile("s_waitcnt vmcnt(6)" ::: "memory")
#define WAIT_VM0()  asm volatile("s_waitcnt vmcnt(0)" ::: "memory")
#define MFMA16(a, b, c) __builtin_amdgcn_mfma_f32_16x16x32_bf16((a), (b), (c), 0, 0, 0)

__global__ __launch_bounds__(512, 2)
void gemm256_8p(const short* __restrict__ A, const short* __restrict__ B,
                unsigned short* __restrict__ C)
{
    __shared__ __align__(1024) char smem[131072];  // [2 buf][A 32KB | B 32KB]
    const int tid  = threadIdx.x;
    const int lane = tid & 63;
    const int wave = tid >> 6;
    const int wr = wave >> 2;          // 0..1  (128-row stripe)
    const int wc = wave & 3;           // 0..3  (64-col stripe)
    const int bx = blockIdx.x & 15, by = blockIdx.x >> 4;
    const int brow = by * 256, bcol = bx * 256;
    const int NT = 32;                 // K=2048 / BK=64

    // per-lane logical byte bases within a [256][64]bf16 region (128B rows)
    const int aBase = (wr * 128 + (lane & 15)) * 128 + ((lane >> 4) << 4);
    const int bBase = (wc * 64  + (lane & 15)) * 128 + ((lane >> 4) << 4);

    f32x4 acc[8][4] = {};
    bf16x8 aF[4][2], bF[2][2][2];

    char* Areg0 = smem;             char* Breg0 = smem + 32768;
    char* Areg1 = smem + 65536;     char* Breg1 = smem + 65536 + 32768;

    // ---- prologue: tile0 fully + {b0,b1,a0}(1); vmcnt(6) leaves those 3 in flight
    stage_half(A, brow +   0, 0, Areg0 +     0, tid);   // a0(0)
    stage_half(A, brow + 128, 0, Areg0 + 16384, tid);   // a1(0)
    stage_half(B, bcol +   0, 0, Breg0 +     0, tid);   // b0(0)
    stage_half(B, bcol + 128, 0, Breg0 + 16384, tid);   // b1(0)
    stage_half(B, bcol +   0, 1, Breg1 +     0, tid);   // b0(1)
    stage_half(B, bcol + 128, 1, Breg1 + 16384, tid);   // b1(1)
    stage_half(A, brow +   0, 1, Areg1 +     0, tid);   // a0(1)
    WAIT_VM6();                                          // tile0 complete
    BARR();

    for (int it = 0; it < 16; ++it) {
        const int t0 = it * 2;
        #pragma unroll
        for (int hb = 0; hb < 2; ++hb) {
            const int t = t0 + hb;
            const char* Ar = hb ? Areg1 : Areg0;   // compute buffer = t&1 = hb
            const char* Br = hb ? Breg1 : Breg0;
            char* ArN = hb ? Areg0 : Areg1;        // buffer of tile t+1
            char* AwC = hb ? Areg1 : Areg0;        // buffer of tile t+2 (= current)
            char* BwC = hb ? Breg1 : Breg0;

            // ---- phase 1: q(mh0,nh0) — 12 ds_reads, stage a1(t+1) [other buf]
            #pragma unroll
            for (int m = 0; m < 4; ++m)
                #pragma unroll
                for (int ks = 0; ks < 2; ++ks)
                    aF[m][ks] = ldsRead(Ar, aBase + m * 2048 + ks * 64);
            #pragma unroll
            for (int n = 0; n < 2; ++n)
                #pragma unroll
                for (int ks = 0; ks < 2; ++ks)
                    bF[0][n][ks] = ldsRead(Br, bBase + n * 2048 + ks * 64);
            if (t + 1 < NT) stage_half(A, brow + 128, t + 1, ArN + 16384, tid);
            BARR(); WAIT_LGKM();
            __builtin_amdgcn_s_setprio(1);
            #pragma unroll
            for (int m = 0; m < 4; ++m)
                #pragma unroll
                for (int n = 0; n < 2; ++n)
                    #pragma unroll
                    for (int ks = 0; ks < 2; ++ks)
                        acc[m][n] = MFMA16(aF[m][ks], bF[0][n][ks], acc[m][n]);
            __builtin_amdgcn_s_setprio(0);
            BARR();

            // ---- phase 2: q(mh0,nh1) — 4 ds_reads, NO stage
            #pragma unroll
            for (int n = 0; n < 2; ++n)
                #pragma unroll
                for (int ks = 0; ks < 2; ++ks)
                    bF[1][n][ks] = ldsRead(Br, bBase + (2 + n) * 2048 + ks * 64);
            BARR(); WAIT_LGKM();
            __builtin_amdgcn_s_setprio(1);
            #pragma unroll
            for (int m = 0; m < 4; ++m)
                #pragma unroll
                for (int n = 0; n < 2; ++n)
                    #pragma unroll
                    for (int ks = 0; ks < 2; ++ks)
                        acc[m][2 + n] = MFMA16(aF[m][ks], bF[1][n][ks], acc[m][2 + n]);
            __builtin_amdgcn_s_setprio(0);
            BARR();

            // ---- phase 3: q(mh1,nh1) — 8 ds_reads (aF-hi), stage b0(t+2)
            #pragma unroll
            for (int m = 0; m < 4; ++m)
                #pragma unroll
                for (int ks = 0; ks < 2; ++ks)
                    aF[m][ks] = ldsRead(Ar, aBase + (4 + m) * 2048 + ks * 64);
            if (t + 2 < NT) stage_half(B, bcol + 0, t + 2, BwC + 0, tid);
            BARR(); WAIT_LGKM();
            __builtin_amdgcn_s_setprio(1);
            #pragma unroll
            for (int m = 0; m < 4; ++m)
                #pragma unroll
                for (int n = 0; n < 2; ++n)
                    #pragma unroll
                    for (int ks = 0; ks < 2; ++ks)
                        acc[4 + m][2 + n] = MFMA16(aF[m][ks], bF[1][n][ks], acc[4 + m][2 + n]);
            __builtin_amdgcn_s_setprio(0);
            BARR();

            // ---- phase 4: q(mh1,nh0) — 0 ds_reads; stage b1(t+2)+a0(t+2); vmcnt(6)
            if (t + 2 < NT) {
                stage_half(B, bcol + 128, t + 2, BwC + 16384, tid);
                stage_half(A, brow +   0, t + 2, AwC +     0, tid);
                WAIT_VM6();     // completes all 4 halves of tile t+1
            } else {
                WAIT_VM0();     // tail drain (tiles 30,31)
            }
            BARR(); WAIT_LGKM();
            __builtin_amdgcn_s_setprio(1);
            #pragma unroll
            for (int m = 0; m < 4; ++m)
                #pragma unroll
                for (int n = 0; n < 2; ++n)
                    #pragma unroll
                    for (int ks = 0; ks < 2; ++ks)
                        acc[4 + m][n] = MFMA16(aF[m][ks], bF[0][n][ks], acc[4 + m][n]);
            __builtin_amdgcn_s_setprio(0);
            BARR();
        }
    }

    // ---- epilogue: C/D layout col=lane&15, row=(lane>>4)*4+j; store bf16
    const int row0 = brow + wr * 128 + ((lane >> 4) << 2);
    const int col0 = bcol + wc * 64 + (lane & 15);
    #pragma unroll
    for (int m = 0; m < 8; ++m)
        #pragma unroll
        for (int n = 0; n < 4; ++n) {
            unsigned short* Cp = C + (size_t)(row0 + m * 16) * 4096 + col0 + n * 16;
            #pragma unroll
            for (int j = 0; j < 4; ++j)
                Cp[(size_t)j * 4096] = (unsigned short)f2bf(acc[m][n][j]);
        }
}

// ---------------------------------------------------------------------------
// Per-row LayerNorm over 4096 bf16 gates + LSTM activations. One block per row.
// ---------------------------------------------------------------------------
__global__ __launch_bounds__(256)
void ln_act_kernel(const unsigned short* __restrict__ gates,
                   const float* __restrict__ b_ih, const float* __restrict__ b_hh,
                   const float* __restrict__ gamma, const float* __restrict__ beta,
                   const float* __restrict__ c,
                   float* __restrict__ out_h, float* __restrict__ out_c)
{
    __shared__ float sg[4096];
    __shared__ float rs[4], rq[4];
    const int b = blockIdx.x;
    const int t = threadIdx.x;
    const uint4*  grow = (const uint4*)(gates + ((long)b << 12));  // 512 x 16B
    const float4* bi4  = (const float4*)b_ih;
    const float4* bh4  = (const float4*)b_hh;

    float sum = 0.f, sq = 0.f;
    #pragma unroll
    for (int j = 0; j < 2; ++j) {
        const int q = t + j * 256;           // uint4 index: 8 bf16 = elems [8q,8q+8)
        uint4 u = grow[q];
        float g8[8] = { lo_bf(u.x), hi_bf(u.x), lo_bf(u.y), hi_bf(u.y),
                        lo_bf(u.z), hi_bf(u.z), lo_bf(u.w), hi_bf(u.w) };
        float4 bi0 = bi4[2 * q], bi1 = bi4[2 * q + 1];
        float4 bh0 = bh4[2 * q], bh1 = bh4[2 * q + 1];
        g8[0] += bi0.x + bh0.x;  g8[1] += bi0.y + bh0.y;
        g8[2] += bi0.z + bh0.z;  g8[3] += bi0.w + bh0.w;
        g8[4] += bi1.x + bh1.x;  g8[5] += bi1.y + bh1.y;
        g8[6] += bi1.z + bh1.z;  g8[7] += bi1.w + bh1.w;
        ((float4*)sg)[2 * q]     = { g8[0], g8[1], g8[2], g8[3] };
        ((float4*)sg)[2 * q + 1] = { g8[4], g8[5], g8[6], g8[7] };
        #pragma unroll
        for (int e = 0; e < 8; ++e) { sum += g8[e]; sq += g8[e] * g8[e]; }
    }
    #pragma unroll
    for (int off = 32; off > 0; off >>= 1) {
        sum += __shfl_down(sum, off);
        sq  += __shfl_down(sq, off);
    }
    if ((t & 63) == 0) { rs[t >> 6] = sum; rq[t >> 6] = sq; }
    __syncthreads();
    sum = rs[0] + rs[1] + rs[2] + rs[3];
    sq  = rq[0] + rq[1] + rq[2] + rq[3];
    const float mu   = sum * (1.f / 4096.f);
    const float rstd = rsqrtf(sq * (1.f / 4096.f) - mu * mu + LN_EPS);

    const float4* sg4 = (const float4*)sg;
    const float4* gm4 = (const float4*)gamma;
    const float4* bt4 = (const float4*)beta;
    float4 vi = sg4[t],        vf = sg4[256 + t];
    float4 vg = sg4[512 + t],  vo = sg4[768 + t];
    float4 gi = gm4[t], gf = gm4[256 + t], gg = gm4[512 + t], go = gm4[768 + t];
    float4 zi = bt4[t], zf = bt4[256 + t], zg = bt4[512 + t], zo = bt4[768 + t];
    float4 cc = ((const float4*)c)[((long)b << 8) + t];
    float4 nh, nc;
    {
        float i0, f0, g0, o0;
        #define DO_COMP(X)                                                    \
            i0 = (vi.X - mu) * rstd * gi.X + zi.X;                            \
            f0 = (vf.X - mu) * rstd * gf.X + zf.X;                            \
            g0 = (vg.X - mu) * rstd * gg.X + zg.X;                            \
            o0 = (vo.X - mu) * rstd * go.X + zo.X;                            \
            nc.X = sigm(f0) * cc.X + sigm(i0) * tanh_f(g0);                   \
            nh.X = sigm(o0) * tanh_f(nc.X);
        DO_COMP(x) DO_COMP(y) DO_COMP(z) DO_COMP(w)
        #undef DO_COMP
    }
    ((float4*)out_h)[((long)b << 8) + t] = nh;
    ((float4*)out_c)[((long)b << 8) + t] = nc;
}

// ---------------------------------------------------------------------------
extern "C" void kernel_launch(void* const* d_in, const int* in_sizes, int n_in,
                              void* d_out, int out_size, void* d_ws, size_t ws_size,
                              hipStream_t stream)
{
    const float* x    = (const float*)d_in[0];
    const float* h    = (const float*)d_in[1];
    const float* c    = (const float*)d_in[2];
    const float* w_ih = (const float*)d_in[3];
    const float* w_hh = (const float*)d_in[4];
    const float* b_ih = (const float*)d_in[5];
    const float* b_hh = (const float*)d_in[6];
    const float* gam  = (const float*)d_in[7];
    const float* bet  = (const float*)d_in[8];
    float* out = (float*)d_out;
    (void)in_sizes; (void)n_in; (void)out_size; (void)ws_size;

    const int B = 4096, H = 1024;

    char*  ws    = (char*)d_ws;
    short* Acat  = (short*)ws;                                       // 16 MiB bf16 [4096][2048]
    short* Wcat  = (short*)(ws + (size_t)16 * 1024 * 1024);          // 16 MiB bf16 [4096][2048]
    unsigned short* gates = (unsigned short*)(ws + (size_t)32 * 1024 * 1024); // 32 MiB bf16 [4096][4096]

    pack_all_bf16<<<2048, 256, 0, stream>>>(x, h, w_ih, w_hh, Acat, Wcat);

    gemm256_8p<<<dim3(256), dim3(512), 0, stream>>>(Acat, Wcat, gates);

    ln_act_kernel<<<B, 256, 0, stream>>>(gates, b_ih, b_hh, gam, bet, c,
                                         out, out + (size_t)B * H);
}